// Round 15
// baseline (135.952 us; speedup 1.0000x reference)
//
#include <hip/hip_runtime.h>

// OESNN_SEPhIA_MultiTiled2: 32-step recurrent SNN, B=8192.
// R15: store densification -- the last untested subsystem. All prior
// theories eliminated by experiment: weight residency (R10), cross-lane
// (R11), occupancy (R3/R9), prefetch depth (R5), load shape (R12/R14),
// load/store vmcnt coupling (R14). Every round issued ~8 exec-masked
// scattered-dword stores per wave-iter (~31 PARTIAL-line L2 write requests,
// read-modify-write merges); fillBuffer hits 6.4 TB/s at the same 8%
// occupancy using full-line dwordx4 -- request shape, not occupancy, is
// the differentiator. Stores backpressure through the finite vmcnt queue
// with no visible waitcnt, fitting 14 rounds of "nothing changes the wall".
// Fix (on the R14 base: LDS x-slab leaves ONLY stores on vmcnt):
//  - pw is reconstructible in ANY lane from ballot bits + pon/poff tables
//    (L1 already does this), so lanes 0..35 store the wave's contiguous
//    144-float pw region as ONE dwordx4 each (full lines) using prologue-
//    precomputed per-lane owner-shift/table constants.
//  - mems0 repacked to the same dense float4 pattern via 3 shfl + select
//    per value (off the recurrent path).
//  - spks1/mems1 already dense (64 consecutive dwords).
// Loop stores: 8 instrs / ~31 partial-line requests -> 4 instrs / ~13
// full-line requests. Values bit-identical to the PASSING R11/R14 (same
// tables, same ballot bits, same mem0 moved verbatim); only the
// lane->address assignment changes.

namespace {
constexpr int Tn = 32;
constexpr int Bn = 8192;
constexpr int O_PW = 0;                       // spks0 (= pw0) [T,B,18]
constexpr int O_S1 = Tn * Bn * 18;            // spks1 [T,B,8]
constexpr int O_M0 = O_S1 + Tn * Bn * 8;      // mems0 [T,B,18]
constexpr int O_M1 = O_M0 + Tn * Bn * 18;     // mems1 [T,B,8]
}

__global__ __launch_bounds__(64, 1)
void oesnn_kernel(const float* __restrict__ x_in,
                  const float* __restrict__ W0g,   // [2,18,18]
                  const float* __restrict__ d0g,   // [2,9]
                  const float* __restrict__ W1g,   // [1,18,16]
                  const float* __restrict__ d1g,   // [1,8]
                  const float* __restrict__ peakg, // [36]
                  float* __restrict__ out)
{
    const int lt  = threadIdx.x;              // lane in wave (block == wave)
    const int b0  = blockIdx.x * 8;           // wave's first batch element
    const int b   = b0 + (lt >> 3);           // this lane's batch element
    const int e   = lt >> 3;                  // element within wave (0..7)
    const int sub = lt & 7;                   // lane within batch group
    const int tl  = sub >> 2;                 // layer-0 tile (0/1)
    const int q   = sub & 3;                  // lane within tile
    const int j0  = (q == 0) ? 0 : (2 * q + 1);   // first in-tile channel
    const int nj  = (q == 0) ? 3 : 2;             // real channel count (pad to 3)

    // x slab: [32 t][8 e][36 ch] floats = 36864 B
    __shared__ float xs[Tn * 288];

    // ---------------- stage ALL x for this wave: dense, each byte once ------
    #pragma unroll 4
    for (int t = 0; t < Tn; ++t) {
        const float4* gs = (const float4*)(x_in + ((size_t)t * Bn + b0) * 36);
        float4* dst = (float4*)(xs + t * 288);
        dst[lt] = gs[lt];
        if (lt < 8) dst[64 + lt] = gs[64 + lt];
    }

    // ---------------- per-lane weight preload into registers ----------------
    float w0e[3][18], w0o[3][18], dd0[3], pon[3], poff[3];
    #pragma unroll
    for (int j = 0; j < 3; ++j) {
        const int jc = (j < nj) ? (j0 + j) : j0;   // clamped dup stays in-lane
        dd0[j] = d0g[tl * 9 + jc];
        #pragma unroll
        for (int w = 0; w < 18; ++w) {
            const float2 p = *(const float2*)(W0g + ((tl * 18 + w) * 18 + 2 * jc));
            w0e[j][w] = p.x;
            w0o[j][w] = p.y;
        }
        // pw0 takes exactly two values per channel: precompute via the
        // reference's complex-division -> abs -> square path (verbatim R2).
        const int c = tl * 9 + jc;
        const float wl    = 1550.0f + 0.8f * (float)c;
        const float halfw = 0.5f * (wl * 1e3f / 15000.0f);
        const float amp   = sqrtf((exp10f(peakg[c] / 10.0f) / 1000.0f) * 1e6f);
        {   // spike = 0: lo = (0.1 + 0i)/(1 + 0i) * amp
            const float lr = 0.1f * amp;
            const float a  = sqrtf(lr * lr);
            poff[j] = a * a;
        }
        {   // spike = 1: delta = -250 / (0.5*fwhm)
            const float delta = -250.0f / halfw;
            const float den = fmaf(delta, delta, 1.0f);
            const float qr  = fmaf(delta, delta, 0.1f) / den;     // (g + d^2)/den
            const float qi  = (delta - 0.1f * delta) / den;       // (d - g*d)/den
            const float lr = qr * amp, li = qi * amp;
            const float a  = sqrtf(fmaf(lr, lr, li * li));
            pon[j] = a * a;
        }
    }

    // layer-1: lane `sub` owns output channel o = sub (columns 2o, 2o+1).
    float w1e[18], w1o[18];
    #pragma unroll
    for (int w = 0; w < 18; ++w) {
        const float2 pp = *(const float2*)(W1g + w * 16 + 2 * sub);  // 8B-aligned
        w1e[w] = pp.x;
        w1o[w] = pp.y;
    }
    const float dd1 = d1g[sub];

    const int basel = lt & ~7;

    // ---------------- prologue-only gather of full pon/poff tables ----------
    float pon_f[18], poff_f[18];
    #pragma unroll
    for (int c = 0; c < 18; ++c) {
        const int tlc = c / 9, jc2 = c % 9;
        const int qo  = (jc2 < 3) ? 0 : ((jc2 - 1) / 2);   // owner lane-in-tile
        const int st  = (qo == 0) ? 0 : (2 * qo + 1);
        const int r   = jc2 - st;                          // owner's reg index
        pon_f[c]  = __shfl(pon[r],  basel + tlc * 4 + qo, 64);
        poff_f[c] = __shfl(poff[r], basel + tlc * 4 + qo, 64);
    }

    // ---------------- dense-store lane constants (lanes 0..35) --------------
    // Storing lane s covers global pw/m0 floats G = 4s..4s+3 of this wave's
    // contiguous 144-float region: elem = G/18, chan = G%18. Precompute per
    // value: owner lane (for shfl / ballot bit), reg-select flags, tables.
    const int ltc = (lt < 36) ? lt : 35;     // clamp idle lanes (never stored)
    int   osh[4], isr0[4], isr1[4];
    float pon_s[4], poff_s[4];
    #pragma unroll
    for (int i = 0; i < 4; ++i) {
        const int G    = 4 * ltc + i;
        const int elem = G / 18, c = G % 18;
        const int tlc  = c / 9, jc2 = c % 9;
        const int qo   = (jc2 < 3) ? 0 : ((jc2 - 1) / 2);
        const int st   = (qo == 0) ? 0 : (2 * qo + 1);
        const int r    = jc2 - st;
        const int OL   = elem * 8 + tlc * 4 + qo;          // owner lane in wave
        osh[i]  = OL;
        isr0[i] = (r == 0);
        isr1[i] = (r == 1);
        const float a0 = __shfl(pon[0],  OL, 64);
        const float a1 = __shfl(pon[1],  OL, 64);
        const float a2 = __shfl(pon[2],  OL, 64);
        pon_s[i]  = isr0[i] ? a0 : (isr1[i] ? a1 : a2);
        const float f0 = __shfl(poff[0], OL, 64);
        const float f1 = __shfl(poff[1], OL, 64);
        const float f2 = __shfl(poff[2], OL, 64);
        poff_s[i] = isr0[i] ? f0 : (isr1[i] ? f1 : f2);
    }

    // ---------------- PIN loop-invariants ----------------
    float dd1p = dd1;
    #pragma unroll
    for (int j = 0; j < 3; ++j) {
        #pragma unroll
        for (int w = 0; w < 18; ++w) {
            asm volatile("" : "+v"(w0e[j][w]));
            asm volatile("" : "+v"(w0o[j][w]));
        }
        asm volatile("" : "+v"(dd0[j]));
    }
    #pragma unroll
    for (int w = 0; w < 18; ++w) {
        asm volatile("" : "+v"(w1e[w]));
        asm volatile("" : "+v"(w1o[w]));
        asm volatile("" : "+v"(pon_f[w]));
        asm volatile("" : "+v"(poff_f[w]));
    }
    #pragma unroll
    for (int i = 0; i < 4; ++i) {
        asm volatile("" : "+v"(pon_s[i]));
        asm volatile("" : "+v"(poff_s[i]));
    }
    asm volatile("" : "+v"(dd1p));

    // ---------------- state & pointers ----------------
    float mem0[3] = {0.f, 0.f, 0.f};
    float mem1 = 0.f;

    float* opw4 = out + O_PW + (size_t)b0 * 18 + 4 * ltc;   // dense pw float4
    float* om04 = out + O_M0 + (size_t)b0 * 18 + 4 * ltc;   // dense m0 float4
    float* os1  = out + O_S1 + (size_t)b * 8 + sub;
    float* om1  = out + O_M1 + (size_t)b * 8 + sub;

    // prefetch t=0 from LDS (same-wave DS in-order after staging writes)
    const float* xb0 = xs + e * 36 + tl * 18;
    float2 xv[9];
    #pragma unroll
    for (int k = 0; k < 9; ++k) xv[k] = *(const float2*)(xb0 + 2 * k);

    #pragma unroll 1
    for (int t = 0; t < Tn; ++t) {
        // unpack current x, scale to optical power (reference: p_in = x * 1e-4)
        float p[18];
        #pragma unroll
        for (int k = 0; k < 9; ++k) {
            p[2 * k]     = xv[k].x * 1e-4f;
            p[2 * k + 1] = xv[k].y * 1e-4f;
        }
        // prefetch next timestep from LDS while computing this one
        if (t < Tn - 1) {
            const float* xb = xs + (t + 1) * 288 + e * 36 + tl * 18;
            #pragma unroll
            for (int k = 0; k < 9; ++k) xv[k] = *(const float2*)(xb + 2 * k);
        }

        // ---- layer 0: even/odd dots, balanced PD, LIF, spike predicate ----
        int spk[3];
        #pragma unroll
        for (int j = 0; j < 3; ++j) {
            float se = 0.f, so = 0.f;
            #pragma unroll
            for (int w = 0; w < 18; ++w) {
                se = fmaf(p[w], w0e[j][w], se);
                so = fmaf(p[w], w0o[j][w], so);
            }
            const float c0 = (se - so) * dd0[j];
            const float m  = mem0[j];
            const float m2 = (m > 0.55f) ? 0.0f : fmaf(0.95f, m, c0);
            mem0[j] = m2;
            spk[j]  = (m2 > 0.55f) ? 1 : 0;
        }

        // ---- spike broadcast via ballot ----
        const unsigned long long bm0 = __ballot(spk[0]);
        const unsigned long long bm1 = __ballot(spk[1]);
        const unsigned long long bm2 = __ballot(spk[2]);

        // ---- dense m0 repack: value i from owner lane osh[i], reg by flags.
        // (off the recurrent path; bpermute issue overlaps L1 compute) ----
        float m0p[4];
        #pragma unroll
        for (int i = 0; i < 4; ++i) {
            const float v0 = __shfl(mem0[0], osh[i], 64);
            const float v1 = __shfl(mem0[1], osh[i], 64);
            const float v2 = __shfl(mem0[2], osh[i], 64);
            m0p[i] = isr0[i] ? v0 : (isr1[i] ? v1 : v2);
        }

        // ---- dense pw rebuild from ballot bits + per-lane tables ----
        float pwp[4];
        #pragma unroll
        for (int i = 0; i < 4; ++i) {
            const unsigned long long bsel =
                isr0[i] ? bm0 : (isr1[i] ? bm1 : bm2);
            const unsigned int bit = (unsigned int)(bsel >> osh[i]) & 1u;
            pwp[i] = bit ? pon_s[i] : poff_s[i];
        }

        // ---- layer 1: rebuild pw_c from bits + tables (bit-identical to
        // R2's pwall[c]), ascending-c single-accumulator fma chains ----
        const unsigned int g0 = (unsigned int)(bm0 >> basel);
        const unsigned int g1 = (unsigned int)(bm1 >> basel);
        const unsigned int g2 = (unsigned int)(bm2 >> basel);
        float i1e = 0.f, i1o = 0.f;
        #pragma unroll
        for (int c = 0; c < 18; ++c) {
            const int tlc = c / 9, jc2 = c % 9;
            const int qo  = (jc2 < 3) ? 0 : ((jc2 - 1) / 2);   // owner lane-in-tile
            const int st  = (qo == 0) ? 0 : (2 * qo + 1);
            const int r   = jc2 - st;                          // owner's reg index
            const unsigned int gm = (r == 0) ? g0 : ((r == 1) ? g1 : g2);
            const float pwc = ((gm >> (tlc * 4 + qo)) & 1u) ? pon_f[c] : poff_f[c];
            i1e = fmaf(pwc, w1e[c], i1e);
            i1o = fmaf(pwc, w1o[c], i1o);
        }

        const float c1 = (i1e - i1o) * dd1p;
        const float m  = mem1;
        const float m2 = (m > 0.25f) ? 0.0f : fmaf(0.95f, m, c1);
        mem1 = m2;

        // ---- 4 dense stores: 2x dwordx4 (36 lanes, full lines) + 2x dword ----
        if (lt < 36) {
            *(float4*)opw4 = make_float4(pwp[0], pwp[1], pwp[2], pwp[3]);
            *(float4*)om04 = make_float4(m0p[0], m0p[1], m0p[2], m0p[3]);
        }
        *os1 = (m2 > 0.25f) ? 1.0f : 0.0f;   // 64 consecutive dwords
        *om1 = m2;

        opw4 += Bn * 18;
        om04 += Bn * 18;
        os1  += Bn * 8;
        om1  += Bn * 8;
    }
}

extern "C" void kernel_launch(void* const* d_in, const int* in_sizes, int n_in,
                              void* d_out, int out_size, void* d_ws, size_t ws_size,
                              hipStream_t stream) {
    (void)in_sizes; (void)n_in; (void)out_size; (void)d_ws; (void)ws_size;
    const float* x  = (const float*)d_in[0];
    const float* W0 = (const float*)d_in[1];
    const float* d0 = (const float*)d_in[2];
    const float* W1 = (const float*)d_in[3];
    const float* d1 = (const float*)d_in[4];
    const float* pk = (const float*)d_in[5];
    float* out = (float*)d_out;

    dim3 grid(Bn / 8), block(64);   // 1024 one-wave blocks, 8 elements each
    hipLaunchKernelGGL(oesnn_kernel, grid, block, 0, stream,
                       x, W0, d0, W1, d1, pk, out);
}

// Round 16
// 117.161 us; speedup vs baseline: 1.1604x; 1.1604x over previous
//
#include <hip/hip_runtime.h>

// OESNN_SEPhIA_MultiTiled2: 32-step recurrent SNN, B=8192.
// R16 = R10 (best measured, ~39.5us kernel) + per-wave entry stagger.
// 15 rounds of single-subsystem experiments all null/negative: weight
// residency (R10 pin), cross-lane (R11 ballot), occupancy (R3/R9),
// prefetch depth (R5), load shape (R12), zero-loads-in-loop (R14),
// vmcnt coupling (R14), store shape (R15). No counter saturated
// (VALUBusy<=48, HBM<=22%). Surviving theory: the 4 co-resident waves per
// CU run the same ~300-instr loop in near-lockstep, fire their memory
// burst in the same ~200cyc window, saturate the CU's single LSU/L1
// request port, and all wait together -- the shared release re-syncs them
// each iteration. Explains: traffic-kind changes never helped (burst just
// changes flavor), more waves hurt (bigger colliding burst), fillBuffer
// hits 6.4TB/s at the same occupancy (no compute gap; queues stay fed).
// Fix: one-time s_sleep stagger at loop entry -- wave w sleeps ~850*w cyc
// (s_sleep 13/27/40) so the four bursts interleave across the ~3300cyc
// iteration. Numerics untouched (sleep is pure scheduling): op-for-op the
// PASSING R10 kernel.

namespace {
constexpr int Tn = 32;
constexpr int Bn = 8192;
constexpr int O_PW = 0;                       // spks0 (= pw0) [T,B,18]
constexpr int O_S1 = Tn * Bn * 18;            // spks1 [T,B,8]
constexpr int O_M0 = O_S1 + Tn * Bn * 8;      // mems0 [T,B,18]
constexpr int O_M1 = O_M0 + Tn * Bn * 18;     // mems1 [T,B,8]
}

__global__ __launch_bounds__(256, 1)
void oesnn_kernel(const float* __restrict__ x_in,
                  const float* __restrict__ W0g,   // [2,18,18]
                  const float* __restrict__ d0g,   // [2,9]
                  const float* __restrict__ W1g,   // [1,18,16]
                  const float* __restrict__ d1g,   // [1,8]
                  const float* __restrict__ peakg, // [36]
                  float* __restrict__ out)
{
    const int lt  = threadIdx.x & 63;         // lane in wave
    const int tid = blockIdx.x * 256 + threadIdx.x;
    const int b   = tid >> 3;                 // batch element
    const int sub = tid & 7;                  // lane within batch group
    const int tl  = sub >> 2;                 // layer-0 tile (0/1)
    const int q   = sub & 3;                  // lane within tile
    const int j0  = (q == 0) ? 0 : (2 * q + 1);   // first in-tile channel
    const int nj  = (q == 0) ? 3 : 2;             // real channel count (pad to 3)

    // ---------------- per-lane weight preload into registers ----------------
    float w0e[3][18], w0o[3][18], dd0[3], pon[3], poff[3];
    #pragma unroll
    for (int j = 0; j < 3; ++j) {
        const int jc = (j < nj) ? (j0 + j) : j0;   // clamped dup stays in-lane
        dd0[j] = d0g[tl * 9 + jc];
        #pragma unroll
        for (int w = 0; w < 18; ++w) {
            const float2 p = *(const float2*)(W0g + ((tl * 18 + w) * 18 + 2 * jc));
            w0e[j][w] = p.x;
            w0o[j][w] = p.y;
        }
        // pw0 takes exactly two values per channel: precompute via the
        // reference's complex-division -> abs -> square path.
        const int c = tl * 9 + jc;
        const float wl    = 1550.0f + 0.8f * (float)c;
        const float halfw = 0.5f * (wl * 1e3f / 15000.0f);
        const float amp   = sqrtf((exp10f(peakg[c] / 10.0f) / 1000.0f) * 1e6f);
        {   // spike = 0: lo = (0.1 + 0i)/(1 + 0i) * amp
            const float lr = 0.1f * amp;
            const float a  = sqrtf(lr * lr);
            poff[j] = a * a;
        }
        {   // spike = 1: delta = -250 / (0.5*fwhm)
            const float delta = -250.0f / halfw;
            const float den = fmaf(delta, delta, 1.0f);
            const float qr  = fmaf(delta, delta, 0.1f) / den;     // (g + d^2)/den
            const float qi  = (delta - 0.1f * delta) / den;       // (d - g*d)/den
            const float lr = qr * amp, li = qi * amp;
            const float a  = sqrtf(fmaf(lr, lr, li * li));
            pon[j] = a * a;
        }
    }

    // layer-1: lane `sub` owns output channel o = sub (columns 2o, 2o+1).
    float w1e[18], w1o[18];
    #pragma unroll
    for (int w = 0; w < 18; ++w) {
        const float2 pp = *(const float2*)(W1g + w * 16 + 2 * sub);  // 8B-aligned
        w1e[w] = pp.x;
        w1o[w] = pp.y;
    }
    const float dd1 = d1g[sub];

    // ---------------- PIN all loop-invariants in VGPRs (cap = 256) ---------
    float dd1p = dd1;
    #pragma unroll
    for (int j = 0; j < 3; ++j) {
        #pragma unroll
        for (int w = 0; w < 18; ++w) {
            asm volatile("" : "+v"(w0e[j][w]));
            asm volatile("" : "+v"(w0o[j][w]));
        }
        asm volatile("" : "+v"(dd0[j]));
        asm volatile("" : "+v"(pon[j]));
        asm volatile("" : "+v"(poff[j]));
    }
    #pragma unroll
    for (int w = 0; w < 18; ++w) {
        asm volatile("" : "+v"(w1e[w]));
        asm volatile("" : "+v"(w1o[w]));
    }
    asm volatile("" : "+v"(dd1p));

    // ---------------- state & pointers ----------------
    float mem0[3] = {0.f, 0.f, 0.f};
    float mem1 = 0.f;

    const float* xb = x_in + (size_t)b * 36 + tl * 18;
    float* opw = out + O_PW + (size_t)b * 18 + tl * 9 + j0;
    float* om0 = out + O_M0 + (size_t)b * 18 + tl * 9 + j0;
    float* os1 = out + O_S1 + (size_t)b * 8 + sub;
    float* om1 = out + O_M1 + (size_t)b * 8 + sub;

    const int basel = lt & ~7;

    // ---------------- depth-2 ping-pong x prefetch ----------------
    float2 xvA[9], xvB[9];
    {
        const float2* s0 = (const float2*)(xb);
        const float2* s1 = (const float2*)(xb + (size_t)Bn * 36);
        #pragma unroll
        for (int k = 0; k < 9; ++k) { xvA[k] = s0[k]; xvB[k] = s1[k]; }
    }

    // ---------------- per-wave entry stagger (the R16 change) --------------
    // The 4 waves of this block are co-resident on one CU. Sleep wave w for
    // ~850*w cycles so the waves' per-iteration memory bursts interleave
    // instead of colliding at the CU's LSU port. One-time scheduling cost;
    // zero effect on computed values.
    {
        const int wvi = (threadIdx.x >> 6) & 3;
        if      (wvi == 1) __builtin_amdgcn_s_sleep(13);
        else if (wvi == 2) __builtin_amdgcn_s_sleep(27);
        else if (wvi == 3) __builtin_amdgcn_s_sleep(40);
    }

    // one timestep: consumes xv, refills it for tcur+2
    auto body = [&](float2 (&xv)[9], int tcur) {
        // p = x * 1e-4, rounded once (identical arithmetic to R2)
        float p[18];
        #pragma unroll
        for (int k = 0; k < 9; ++k) {
            p[2 * k]     = xv[k].x * 1e-4f;
            p[2 * k + 1] = xv[k].y * 1e-4f;
        }
        // refill this buffer for tcur+2 (deep prefetch)
        if (tcur + 2 < Tn) {
            const float2* s = (const float2*)(xb + (size_t)(tcur + 2) * Bn * 36);
            #pragma unroll
            for (int k = 0; k < 9; ++k) xv[k] = s[k];
        }

        // ---- layer 0: even/odd column dots, balanced PD, LIF, MRR power ----
        float pwv[3];
        #pragma unroll
        for (int j = 0; j < 3; ++j) {
            float se = 0.f, so = 0.f;
            #pragma unroll
            for (int w = 0; w < 18; ++w) {
                se = fmaf(p[w], w0e[j][w], se);
                so = fmaf(p[w], w0o[j][w], so);
            }
            const float c0 = (se - so) * dd0[j];
            const float m  = mem0[j];
            const float m2 = (m > 0.55f) ? 0.0f : fmaf(0.95f, m, c0);
            mem0[j] = m2;
            pwv[j]  = (m2 > 0.55f) ? pon[j] : poff[j];
        }

        // store pw0 / mem0 (guard the dup channel on 2-channel lanes)
        #pragma unroll
        for (int j = 0; j < 3; ++j) {
            if (j < nj) {
                opw[j] = pwv[j];
                om0[j] = mem0[j];
            }
        }

        // ---- cross-lane gather of all 18 pw values (verbatim R2) ----
        float pwall[18];
        #pragma unroll
        for (int c = 0; c < 18; ++c) {
            const int tlc = c / 9, jc2 = c % 9;
            const int qo  = (jc2 < 3) ? 0 : ((jc2 - 1) / 2);   // owner lane-in-tile
            const int st  = (qo == 0) ? 0 : (2 * qo + 1);
            const int r   = jc2 - st;                          // owner's reg index
            pwall[c] = __shfl(pwv[r], basel + tlc * 4 + qo, 64);
        }

        // ---- layer 1: ascending-w fma into this lane's 2 columns ----
        float i1e = 0.f, i1o = 0.f;
        #pragma unroll
        for (int w = 0; w < 18; ++w) {
            i1e = fmaf(pwall[w], w1e[w], i1e);
            i1o = fmaf(pwall[w], w1o[w], i1o);
        }

        const float c1 = (i1e - i1o) * dd1p;
        const float m  = mem1;
        const float m2 = (m > 0.25f) ? 0.0f : fmaf(0.95f, m, c1);
        mem1 = m2;
        *os1 = (m2 > 0.25f) ? 1.0f : 0.0f;   // 64 lanes -> 64 consecutive dwords
        *om1 = m2;

        opw += Bn * 18;
        om0 += Bn * 18;
        os1 += Bn * 8;
        om1 += Bn * 8;
    };

    #pragma unroll 1
    for (int t = 0; t < Tn; t += 2) {
        body(xvA, t);
        body(xvB, t + 1);
    }
}

extern "C" void kernel_launch(void* const* d_in, const int* in_sizes, int n_in,
                              void* d_out, int out_size, void* d_ws, size_t ws_size,
                              hipStream_t stream) {
    (void)in_sizes; (void)n_in; (void)out_size; (void)d_ws; (void)ws_size;
    const float* x  = (const float*)d_in[0];
    const float* W0 = (const float*)d_in[1];
    const float* d0 = (const float*)d_in[2];
    const float* W1 = (const float*)d_in[3];
    const float* d1 = (const float*)d_in[4];
    const float* pk = (const float*)d_in[5];
    float* out = (float*)d_out;

    dim3 grid(Bn * 8 / 256), block(256);   // 65536 threads = 1024 waves
    hipLaunchKernelGGL(oesnn_kernel, grid, block, 0, stream,
                       x, W0, d0, W1, d1, pk, out);
}